// Round 3
// baseline (330.443 us; speedup 1.0000x reference)
//
#include <hip/hip_runtime.h>
#include <stdint.h>

#define B_SZ 8192
#define N_F 12
#define H_DIM 512
#define K_DIM 1024
#define V_DIM 256

typedef __attribute__((ext_vector_type(8))) __bf16 bf16x8;
typedef __attribute__((ext_vector_type(4))) float f32x4;

// tanh-approx GELU in sigmoid form; |err| vs exact erf-GELU ~1e-3 << 4.6e-2.
__device__ inline float gelu_f(float x) {
  float t = 1.5957691216057308f * x * (1.0f + 0.044715f * x * x);
  return x / (1.0f + __expf(-t));
}

__device__ inline void gld_lds16(const void* g, void* l) {
  __builtin_amdgcn_global_load_lds(
      (const __attribute__((address_space(1))) void*)g,
      (__attribute__((address_space(3))) void*)l, 16, 0, 0);
}

// ---------------------------------------------------------------------------
// Kernel 1 (v3): wave-per-row, three phases to maximize ILP:
//   P1: gather cumsum, record per-lane (s,q) partials for all 12 n (no shfl)
//   P2: ONE batched butterfly over 26 independent values (2 ctx + 24)
//   P3: re-walk cumsum (tab L1/L2-hot), GELU+swizzled bf16x8 stores
// No min-waves bound that would cap VGPRs at 64 (R2's spill bug).
// act2: bf16 [N][B][H], 16B-chunk XOR-swizzled by (b&7) within 8-chunk groups.
// ---------------------------------------------------------------------------
__global__ __launch_bounds__(256, 4) void k_prep(
    const float* __restrict__ ie, const int* __restrict__ feat,
    const float* __restrict__ tab, const float* __restrict__ gam,
    const float* __restrict__ bet, __bf16* __restrict__ act2,
    float* __restrict__ stats) {
  const int lane = threadIdx.x & 63;
  const int b = blockIdx.x * 4 + (threadIdx.x >> 6);

  const float* cb = ie + (size_t)b * H_DIM + lane * 8;
  const float4 c0 = *(const float4*)cb;
  const float4 c1 = *(const float4*)(cb + 4);
  float sc = c0.x + c0.y + c0.z + c0.w + c1.x + c1.y + c1.z + c1.w;
  float qc = c0.x * c0.x + c0.y * c0.y + c0.z * c0.z + c0.w * c0.w +
             c1.x * c1.x + c1.y * c1.y + c1.z * c1.z + c1.w * c1.w;

  int f[N_F - 1];
  const int* fr = feat + b * N_F;
#pragma unroll
  for (int n = 0; n < N_F - 1; ++n) f[n] = fr[n];

  // ---- P1: per-lane partials for all n ----
  float r[8];
#pragma unroll
  for (int i = 0; i < 8; ++i) r[i] = 0.f;
  float snl[N_F], qnl[N_F];
#pragma unroll
  for (int n = 0; n < N_F; ++n) {
    float s = 0.f, q = 0.f;
#pragma unroll
    for (int i = 0; i < 8; ++i) { s += r[i]; q += r[i] * r[i]; }
    snl[n] = s;
    qnl[n] = q;
    if (n < N_F - 1) {
      const float* tr = tab + ((size_t)n * V_DIM + f[n]) * H_DIM + lane * 8;
      const float4 t0 = *(const float4*)tr;
      const float4 t1 = *(const float4*)(tr + 4);
      r[0] += t0.x; r[1] += t0.y; r[2] += t0.z; r[3] += t0.w;
      r[4] += t1.x; r[5] += t1.y; r[6] += t1.z; r[7] += t1.w;
    }
  }

  // ---- P2: batched butterflies (26 independent chains) ----
#pragma unroll
  for (int o = 1; o < 64; o <<= 1) {
    sc += __shfl_xor(sc, o, 64);
    qc += __shfl_xor(qc, o, 64);
#pragma unroll
    for (int n = 0; n < N_F; ++n) {
      snl[n] += __shfl_xor(snl[n], o, 64);
      qnl[n] += __shfl_xor(qnl[n], o, 64);
    }
  }

  float mean[N_F], rsg[N_F];
#pragma unroll
  for (int n = 0; n < N_F; ++n) {
    const float m = (sc + snl[n]) * (1.0f / 1024.0f);
    const float var = (qc + qnl[n]) * (1.0f / 1024.0f) - m * m;
    mean[n] = m;
    rsg[n] = rsqrtf(var + 1e-5f);
  }
  if (lane == 0) {
    float* sp = stats + (size_t)b * N_F * 2;
#pragma unroll
    for (int n = 0; n < N_F; ++n)
      *(float2*)(sp + n * 2) = make_float2(mean[n], rsg[n]);
  }

  // ---- P3: re-walk + GELU + swizzled stores ----
  const float4 g0 = *(const float4*)(gam + H_DIM + lane * 8);
  const float4 g1 = *(const float4*)(gam + H_DIM + lane * 8 + 4);
  const float4 e0 = *(const float4*)(bet + H_DIM + lane * 8);
  const float4 e1 = *(const float4*)(bet + H_DIM + lane * 8 + 4);
  const float ga[8] = {g0.x, g0.y, g0.z, g0.w, g1.x, g1.y, g1.z, g1.w};
  const float be[8] = {e0.x, e0.y, e0.z, e0.w, e1.x, e1.y, e1.z, e1.w};

#pragma unroll
  for (int i = 0; i < 8; ++i) r[i] = 0.f;
  const int sw = (lane & ~7) | ((lane & 7) ^ (b & 7));
  __bf16* arow = act2 + (size_t)b * H_DIM + sw * 8;

#pragma unroll
  for (int n = 0; n < N_F; ++n) {
    const float m = mean[n], rs = rsg[n];
    bf16x8 pk;
#pragma unroll
    for (int i = 0; i < 8; ++i)
      pk[i] = (__bf16)gelu_f((r[i] - m) * rs * ga[i] + be[i]);
    *(bf16x8*)(arow + (size_t)n * B_SZ * H_DIM) = pk;
    if (n < N_F - 1) {
      const float* tr = tab + ((size_t)n * V_DIM + f[n]) * H_DIM + lane * 8;
      const float4 t0 = *(const float4*)tr;
      const float4 t1 = *(const float4*)(tr + 4);
      r[0] += t0.x; r[1] += t0.y; r[2] += t0.z; r[3] += t0.w;
      r[4] += t1.x; r[5] += t1.y; r[6] += t1.z; r[7] += t1.w;
    }
  }
}

// ---------------------------------------------------------------------------
// Kernel 2: pred_W [N][K][V] fp32 -> Wt [N][V][K] bf16, chunk-swizzled by v&7.
// ---------------------------------------------------------------------------
__global__ __launch_bounds__(256) void k_wt(const float* __restrict__ W,
                                            __bf16* __restrict__ Wt) {
  __shared__ float tile[32][33];
  const int bid = blockIdx.x;
  const int n = bid >> 8;
  const int rem = bid & 255;
  const int kt = rem >> 3, vt = rem & 7;
  const int tx = threadIdx.x & 31, ty = threadIdx.x >> 5;
  const float* src = W + (size_t)n * K_DIM * V_DIM;
#pragma unroll
  for (int i = 0; i < 4; ++i) {
    const int k = kt * 32 + ty + i * 8;
    tile[ty + i * 8][tx] = src[(size_t)k * V_DIM + vt * 32 + tx];
  }
  __syncthreads();
  __bf16* dst = Wt + (size_t)n * V_DIM * K_DIM;
  const int t = threadIdx.x;
  if (t < 128) {
    const int v_l = t >> 2, c_l = t & 3;
    const int v = vt * 32 + v_l;
    bf16x8 pk;
#pragma unroll
    for (int e = 0; e < 8; ++e) pk[e] = (__bf16)tile[c_l * 8 + e][v_l];
    const int gc = kt * 4 + c_l;
    const int swc = (gc & ~7) | ((gc & 7) ^ (v & 7));
    *(bf16x8*)(dst + (size_t)v * K_DIM + swc * 8) = pk;
  }
}

// ---------------------------------------------------------------------------
// Kernel 3: fused A-gen + GEMM, 128x256 tile, XOR-swizzled LDS, and an
// LDS-repacked float4-coalesced epilogue (reuses the 48KB tile memory).
// ---------------------------------------------------------------------------
__global__ __launch_bounds__(512, 4) void k_gemm(
    const float* __restrict__ ie, const __bf16* __restrict__ act2,
    const __bf16* __restrict__ Wt, const float* __restrict__ stats,
    const float* __restrict__ gam, const float* __restrict__ bet,
    const float* __restrict__ bias, float* __restrict__ out) {
  constexpr int BM = 128, BN = 256, BK = 64;
  __shared__ __align__(16) char smem[49152];  // As 16K | Ws 32K; epi: f32[32][260]
  __bf16* As = (__bf16*)smem;
  __bf16* Ws = (__bf16*)(smem + BM * BK * 2);
  float* ldsf = (float*)smem;
  __shared__ float muL[BM], rsL[BM];

  const int n = blockIdx.y;
  const int b0 = blockIdx.x * BM;
  const int t = threadIdx.x;
  const int lane = t & 63;
  const int w = t >> 6;
  const int wm = w & 1;
  const int wn = w >> 1;
  const int l15 = lane & 15;
  const int lq = lane >> 4;

  if (t < 2 * BM) {
    const int r = t >> 1, which = t & 1;
    const float v = stats[((size_t)(b0 + r) * N_F + n) * 2 + which];
    if (which == 0) muL[r] = v; else rsL[r] = v;
  }

  f32x4 acc[4][4];
#pragma unroll
  for (int i = 0; i < 4; ++i)
#pragma unroll
    for (int j = 0; j < 4; ++j) acc[i][j] = (f32x4){0.f, 0.f, 0.f, 0.f};

  const __bf16* act2n = act2 + (size_t)n * B_SZ * H_DIM;
  const __bf16* Wtn = Wt + (size_t)n * V_DIM * K_DIM;

  const int o8 = t & 7;
  const int rA = t >> 3;
  const int lr8 = lane >> 3;
  const int lo8 = lane & 7;

  for (int kt = 0; kt < 16; ++kt) {
    const int k0 = kt * BK;
    __syncthreads();
#pragma unroll
    for (int p = 0; p < 4; ++p) {
      const int v0 = w * 32 + p * 8;
      gld_lds16(Wtn + (size_t)(v0 + lr8) * K_DIM + k0 + lo8 * 8, Ws + v0 * BK);
    }
    if (k0 < H_DIM) {
      const int kk = k0 + o8 * 8;
      const float4 gg0 = *(const float4*)(gam + kk);
      const float4 gg1 = *(const float4*)(gam + kk + 4);
      const float4 bt0 = *(const float4*)(bet + kk);
      const float4 bt1 = *(const float4*)(bet + kk + 4);
      const int swo = (o8 ^ (rA & 7)) * 8;
#pragma unroll
      for (int half = 0; half < 2; ++half) {
        const int r = rA + half * 64;
        const float* cp = ie + (size_t)(b0 + r) * H_DIM + kk;
        const float4 x0 = *(const float4*)cp;
        const float4 x1 = *(const float4*)(cp + 4);
        const float mu = muL[r], rs = rsL[r];
        bf16x8 pk;
        pk[0] = (__bf16)gelu_f((x0.x - mu) * rs * gg0.x + bt0.x);
        pk[1] = (__bf16)gelu_f((x0.y - mu) * rs * gg0.y + bt0.y);
        pk[2] = (__bf16)gelu_f((x0.z - mu) * rs * gg0.z + bt0.z);
        pk[3] = (__bf16)gelu_f((x0.w - mu) * rs * gg0.w + bt0.w);
        pk[4] = (__bf16)gelu_f((x1.x - mu) * rs * gg1.x + bt1.x);
        pk[5] = (__bf16)gelu_f((x1.y - mu) * rs * gg1.y + bt1.y);
        pk[6] = (__bf16)gelu_f((x1.z - mu) * rs * gg1.z + bt1.z);
        pk[7] = (__bf16)gelu_f((x1.w - mu) * rs * gg1.w + bt1.w);
        *(bf16x8*)(As + r * BK + swo) = pk;
      }
    } else {
#pragma unroll
      for (int p = 0; p < 2; ++p) {
        const int r0 = w * 16 + p * 8;
        gld_lds16(act2n + (size_t)(b0 + r0 + lr8) * H_DIM + (k0 - H_DIM) + lo8 * 8,
                  As + r0 * BK);
      }
    }
    __syncthreads();
#pragma unroll
    for (int ks = 0; ks < 2; ++ks) {
      const int cs = ks * 4 + lq;
      bf16x8 af[4], bb[4];
#pragma unroll
      for (int i = 0; i < 4; ++i) {
        const int row = wm * 64 + i * 16 + l15;
        af[i] = *(const bf16x8*)(As + row * BK + ((cs ^ (row & 7)) << 3));
      }
#pragma unroll
      for (int j = 0; j < 4; ++j) {
        const int row = wn * 64 + j * 16 + l15;
        bb[j] = *(const bf16x8*)(Ws + row * BK + ((cs ^ (row & 7)) << 3));
      }
#pragma unroll
      for (int i = 0; i < 4; ++i)
#pragma unroll
        for (int j = 0; j < 4; ++j)
          acc[i][j] =
              __builtin_amdgcn_mfma_f32_16x16x32_bf16(af[i], bb[j], acc[i][j], 0, 0, 0);
    }
  }

  // ---- epilogue: LDS repack -> float4 coalesced stores ----
  float bv[4];
#pragma unroll
  for (int j = 0; j < 4; ++j) bv[j] = bias[n * V_DIM + wn * 64 + j * 16 + l15];

  const int erow = t >> 4;                        // 0..31
  const int ecol0 = (t & 15) * 4;                 // 0..60
#pragma unroll
  for (int i = 0; i < 4; ++i) {
    __syncthreads();  // done with previous ldsf reads / K-loop LDS
#pragma unroll
    for (int j = 0; j < 4; ++j) {
      const int col = wn * 64 + j * 16 + l15;
      const int lr = wm * 16 + lq * 4;
#pragma unroll
      for (int r = 0; r < 4; ++r)
        ldsf[(lr + r) * 260 + col] = acc[i][j][r] + bv[j];
    }
    __syncthreads();
    const int grow = b0 + (erow < 16 ? (i * 16 + erow) : (64 + i * 16 + erow - 16));
    float* orow = out + ((size_t)grow * N_F + n) * V_DIM;
#pragma unroll
    for (int c = 0; c < 4; ++c) {
      const int col = ecol0 + c * 64;
      *(float4*)(orow + col) = *(const float4*)(ldsf + erow * 260 + col);
    }
  }
}

// ---------------------------------------------------------------------------
extern "C" void kernel_launch(void* const* d_in, const int* in_sizes, int n_in,
                              void* d_out, int out_size, void* d_ws, size_t ws_size,
                              hipStream_t stream) {
  const float* ie = (const float*)d_in[0];
  const int* feat = (const int*)d_in[1];
  const float* tab = (const float*)d_in[2];
  const float* gam = (const float*)d_in[3];
  const float* bet = (const float*)d_in[4];
  const float* predW = (const float*)d_in[5];
  const float* predb = (const float*)d_in[6];
  float* out = (float*)d_out;

  char* ws = (char*)d_ws;
  __bf16* act2 = (__bf16*)ws;                        // 100,663,296 B
  float* stats = (float*)(ws + 100663296);           //     786,432 B
  __bf16* Wt = (__bf16*)(ws + 100663296 + 786432);   //   6,291,456 B

  hipLaunchKernelGGL(k_prep, dim3(B_SZ / 4), dim3(256), 0, stream, ie, feat,
                     tab, gam, bet, act2, stats);
  hipLaunchKernelGGL(k_wt, dim3(3072), dim3(256), 0, stream, predW, Wt);
  hipLaunchKernelGGL(k_gemm, dim3(B_SZ / 128, N_F), dim3(512), 0, stream, ie,
                     act2, Wt, stats, gam, bet, predb, out);
}

// Round 4
// 292.047 us; speedup vs baseline: 1.1315x; 1.1315x over previous
//
#include <hip/hip_runtime.h>
#include <stdint.h>

#define B_SZ 8192
#define N_F 12
#define H_DIM 512
#define K_DIM 1024
#define V_DIM 256

typedef __attribute__((ext_vector_type(8))) __bf16 bf16x8;
typedef __attribute__((ext_vector_type(4))) float f32x4;

// tanh-approx GELU in sigmoid form; |err| vs exact erf-GELU ~1e-3 << 4.6e-2.
__device__ inline float gelu_f(float x) {
  float t = 1.5957691216057308f * x * (1.0f + 0.044715f * x * x);
  return x / (1.0f + __expf(-t));
}

__device__ inline void gld_lds16(const void* g, void* l) {
  __builtin_amdgcn_global_load_lds(
      (const __attribute__((address_space(1))) void*)g,
      (__attribute__((address_space(3))) void*)l, 16, 0, 0);
}

// ---------------------------------------------------------------------------
// Kernel 1 (v4): wave-per-row, SINGLE pass (R2 structure — best so far), but
// writes BOTH halves of the activation: act bf16 [N][B][1024] where
// [0:512) = gelu(LN(ctx)) and [512:1024) = gelu(LN(masked_sum)).
// 16B chunks XOR-swizzled by (b&7) within each 8-chunk (64-elem) group so
// k_gemm's contiguous global_load_lds lands conflict-free in LDS.
// launch_bounds(256,4): 128-VGPR budget; live set ~75 regs — no spill.
// ---------------------------------------------------------------------------
__global__ __launch_bounds__(256, 4) void k_prep(
    const float* __restrict__ ie, const int* __restrict__ feat,
    const float* __restrict__ tab, const float* __restrict__ gam,
    const float* __restrict__ bet, __bf16* __restrict__ act) {
  const int lane = threadIdx.x & 63;
  const int b = blockIdx.x * 4 + (threadIdx.x >> 6);

  // ctx: lane owns dims [lane*8, lane*8+8) of both halves
  const float* cb = ie + (size_t)b * H_DIM + lane * 8;
  const float4 c0 = *(const float4*)cb;
  const float4 c1 = *(const float4*)(cb + 4);
  const float c[8] = {c0.x, c0.y, c0.z, c0.w, c1.x, c1.y, c1.z, c1.w};
  float sc = c[0] + c[1] + c[2] + c[3] + c[4] + c[5] + c[6] + c[7];
  float qc = c[0] * c[0] + c[1] * c[1] + c[2] * c[2] + c[3] * c[3] +
             c[4] * c[4] + c[5] * c[5] + c[6] * c[6] + c[7] * c[7];
#pragma unroll
  for (int o = 1; o < 64; o <<= 1) {
    sc += __shfl_xor(sc, o, 64);
    qc += __shfl_xor(qc, o, 64);
  }

  const float4 ga0 = *(const float4*)(gam + lane * 8);
  const float4 ga1 = *(const float4*)(gam + lane * 8 + 4);
  const float4 eb0 = *(const float4*)(bet + lane * 8);
  const float4 eb1 = *(const float4*)(bet + lane * 8 + 4);
  const float g1[8] = {ga0.x, ga0.y, ga0.z, ga0.w, ga1.x, ga1.y, ga1.z, ga1.w};
  const float b1[8] = {eb0.x, eb0.y, eb0.z, eb0.w, eb1.x, eb1.y, eb1.z, eb1.w};
  const float4 gb0 = *(const float4*)(gam + H_DIM + lane * 8);
  const float4 gb1 = *(const float4*)(gam + H_DIM + lane * 8 + 4);
  const float4 fb0 = *(const float4*)(bet + H_DIM + lane * 8);
  const float4 fb1 = *(const float4*)(bet + H_DIM + lane * 8 + 4);
  const float g2[8] = {gb0.x, gb0.y, gb0.z, gb0.w, gb1.x, gb1.y, gb1.z, gb1.w};
  const float b2[8] = {fb0.x, fb0.y, fb0.z, fb0.w, fb1.x, fb1.y, fb1.z, fb1.w};

  float r[8];
#pragma unroll
  for (int i = 0; i < 8; ++i) r[i] = 0.f;

  // swizzled 16B-chunk slot (same lane&7 pattern for both halves)
  const int sw = (lane & ~7) | ((lane & 7) ^ (b & 7));
  const int fbase = b * N_F;

  for (int n = 0; n < N_F; ++n) {
    float s = 0.f, q = 0.f;
#pragma unroll
    for (int i = 0; i < 8; ++i) { s += r[i]; q += r[i] * r[i]; }
#pragma unroll
    for (int o = 1; o < 64; o <<= 1) {
      s += __shfl_xor(s, o, 64);
      q += __shfl_xor(q, o, 64);
    }
    const float mean = (sc + s) * (1.0f / 1024.0f);
    const float var = (qc + q) * (1.0f / 1024.0f) - mean * mean;
    const float rs = rsqrtf(var + 1e-5f);

    __bf16* arow = act + ((size_t)n * B_SZ + b) * K_DIM;
    bf16x8 p1, p2;
#pragma unroll
    for (int i = 0; i < 8; ++i)
      p1[i] = (__bf16)gelu_f((c[i] - mean) * rs * g1[i] + b1[i]);
#pragma unroll
    for (int i = 0; i < 8; ++i)
      p2[i] = (__bf16)gelu_f((r[i] - mean) * rs * g2[i] + b2[i]);
    *(bf16x8*)(arow + sw * 8) = p1;
    *(bf16x8*)(arow + H_DIM + sw * 8) = p2;

    if (n < N_F - 1) {
      const int f = feat[fbase + n];
      const float* tr = tab + ((size_t)n * V_DIM + f) * H_DIM + lane * 8;
      const float4 t0 = *(const float4*)tr;
      const float4 t1 = *(const float4*)(tr + 4);
      r[0] += t0.x; r[1] += t0.y; r[2] += t0.z; r[3] += t0.w;
      r[4] += t1.x; r[5] += t1.y; r[6] += t1.z; r[7] += t1.w;
    }
  }
}

// ---------------------------------------------------------------------------
// Kernel 2: pred_W [N][K][V] fp32 -> Wt [N][V][K] bf16, chunk-swizzled by v&7.
// ---------------------------------------------------------------------------
__global__ __launch_bounds__(256) void k_wt(const float* __restrict__ W,
                                            __bf16* __restrict__ Wt) {
  __shared__ float tile[32][33];
  const int bid = blockIdx.x;
  const int n = bid >> 8;
  const int rem = bid & 255;
  const int kt = rem >> 3, vt = rem & 7;
  const int tx = threadIdx.x & 31, ty = threadIdx.x >> 5;
  const float* src = W + (size_t)n * K_DIM * V_DIM;
#pragma unroll
  for (int i = 0; i < 4; ++i) {
    const int k = kt * 32 + ty + i * 8;
    tile[ty + i * 8][tx] = src[(size_t)k * V_DIM + vt * 32 + tx];
  }
  __syncthreads();
  __bf16* dst = Wt + (size_t)n * V_DIM * K_DIM;
  const int t = threadIdx.x;
  if (t < 128) {
    const int v_l = t >> 2, c_l = t & 3;
    const int v = vt * 32 + v_l;
    bf16x8 pk;
#pragma unroll
    for (int e = 0; e < 8; ++e) pk[e] = (__bf16)tile[c_l * 8 + e][v_l];
    const int gc = kt * 4 + c_l;
    const int swc = (gc & ~7) | ((gc & 7) ^ (v & 7));
    *(bf16x8*)(dst + (size_t)v * K_DIM + swc * 8) = pk;
  }
}

// ---------------------------------------------------------------------------
// Kernel 3 (v4): PURE GEMM, m97 structure. grid = (B/128, N), 512 threads.
// BM=128 x BN=256(=V), BK=64, 16 uniform K-iters, ALL staging via
// global_load_lds dwordx4 (both operands pre-swizzled bf16 in global).
// No stats, no GELU, no fp32 loads in the loop. Direct scattered epilogue.
// ---------------------------------------------------------------------------
__global__ __launch_bounds__(512, 4) void k_gemm(
    const __bf16* __restrict__ act, const __bf16* __restrict__ Wt,
    const float* __restrict__ bias, float* __restrict__ out) {
  constexpr int BM = 128, BN = 256, BK = 64;
  __shared__ __align__(16) __bf16 As[BM * BK];  // 16 KB
  __shared__ __align__(16) __bf16 Ws[BN * BK];  // 32 KB

  const int n = blockIdx.y;
  const int b0 = blockIdx.x * BM;
  const int t = threadIdx.x;
  const int lane = t & 63;
  const int w = t >> 6;
  const int wm = w & 1;
  const int wn = w >> 1;
  const int l15 = lane & 15;
  const int lq = lane >> 4;

  f32x4 acc[4][4];
#pragma unroll
  for (int i = 0; i < 4; ++i)
#pragma unroll
    for (int j = 0; j < 4; ++j) acc[i][j] = (f32x4){0.f, 0.f, 0.f, 0.f};

  const __bf16* actn = act + ((size_t)n * B_SZ + b0) * K_DIM;
  const __bf16* Wtn = Wt + (size_t)n * V_DIM * K_DIM;

  const int lr8 = lane >> 3;  // 0..7
  const int lo8 = lane & 7;   // 0..7

  for (int kt = 0; kt < 16; ++kt) {
    const int k0 = kt * BK;
    __syncthreads();
    // stage W tile: wave w covers v rows [w*32, w*32+32), 4 gld insts
#pragma unroll
    for (int p = 0; p < 4; ++p) {
      const int v0 = w * 32 + p * 8;
      gld_lds16(Wtn + (size_t)(v0 + lr8) * K_DIM + k0 + lo8 * 8, Ws + v0 * BK);
    }
    // stage A tile: wave w covers rows [w*16, w*16+16), 2 gld insts
#pragma unroll
    for (int p = 0; p < 2; ++p) {
      const int r0 = w * 16 + p * 8;
      gld_lds16(actn + (size_t)(r0 + lr8) * K_DIM + k0 + lo8 * 8, As + r0 * BK);
    }
    __syncthreads();
#pragma unroll
    for (int ks = 0; ks < 2; ++ks) {
      const int cs = ks * 4 + lq;  // logical 16B-chunk within the BK group
      bf16x8 af[4], bb[4];
#pragma unroll
      for (int i = 0; i < 4; ++i) {
        const int row = wm * 64 + i * 16 + l15;
        af[i] = *(const bf16x8*)(As + row * BK + ((cs ^ (row & 7)) << 3));
      }
#pragma unroll
      for (int j = 0; j < 4; ++j) {
        const int row = wn * 64 + j * 16 + l15;
        bb[j] = *(const bf16x8*)(Ws + row * BK + ((cs ^ (row & 7)) << 3));
      }
#pragma unroll
      for (int i = 0; i < 4; ++i)
#pragma unroll
        for (int j = 0; j < 4; ++j)
          acc[i][j] =
              __builtin_amdgcn_mfma_f32_16x16x32_bf16(af[i], bb[j], acc[i][j], 0, 0, 0);
    }
  }

  // epilogue: C/D layout col=lane&15, row=(lane>>4)*4+reg
#pragma unroll
  for (int j = 0; j < 4; ++j) {
    const int v = wn * 64 + j * 16 + l15;
    const float bv = bias[n * V_DIM + v];
#pragma unroll
    for (int i = 0; i < 4; ++i) {
      const int rb = wm * 64 + i * 16 + lq * 4;
#pragma unroll
      for (int r = 0; r < 4; ++r) {
        out[((size_t)(b0 + rb + r) * N_F + n) * V_DIM + v] = acc[i][j][r] + bv;
      }
    }
  }
}

// ---------------------------------------------------------------------------
extern "C" void kernel_launch(void* const* d_in, const int* in_sizes, int n_in,
                              void* d_out, int out_size, void* d_ws, size_t ws_size,
                              hipStream_t stream) {
  const float* ie = (const float*)d_in[0];
  const int* feat = (const int*)d_in[1];
  const float* tab = (const float*)d_in[2];
  const float* gam = (const float*)d_in[3];
  const float* bet = (const float*)d_in[4];
  const float* predW = (const float*)d_in[5];
  const float* predb = (const float*)d_in[6];
  float* out = (float*)d_out;

  // ws layout (207,618,048 B):
  //   act bf16 [N][B][1024] = 201,326,592 B   (both halves, swizzled)
  //   Wt  bf16 [N][V][K]    =   6,291,456 B
  char* ws = (char*)d_ws;
  __bf16* act = (__bf16*)ws;
  __bf16* Wt = (__bf16*)(ws + 201326592);

  hipLaunchKernelGGL(k_prep, dim3(B_SZ / 4), dim3(256), 0, stream, ie, feat,
                     tab, gam, bet, act);
  hipLaunchKernelGGL(k_wt, dim3(3072), dim3(256), 0, stream, predW, Wt);
  hipLaunchKernelGGL(k_gemm, dim3(B_SZ / 128, N_F), dim3(512), 0, stream, act,
                     Wt, predb, out);
}